// Round 7
// baseline (406.860 us; speedup 1.0000x reference)
//
#include <hip/hip_runtime.h>

#define N_NODES 100000
#define N_EDGES 1600000
#define IN_CH   64
#define HID_CH  64
#define OUT_CH  128
#define NPB     100    // nodes per edge-block (1000 blocks x 100 = 100K exact)

typedef __attribute__((ext_vector_type(8))) __bf16    bf16x8;
typedef __attribute__((ext_vector_type(4))) float     f32x4;
typedef __attribute__((ext_vector_type(2))) _Float16  f16x2;
typedef __attribute__((ext_vector_type(8))) _Float16  f16x8;

__device__ __forceinline__ unsigned short f2bf(float f) {
    union { float f; unsigned int i; } c;
    c.f = f;
    unsigned int u = c.i;
    unsigned int r = (u + 0x7FFFu + ((u >> 16) & 1u)) >> 16;   // RNE
    return (unsigned short)r;
}

// ---------- prep: x fp32->bf16, node-type byte table, zero deg ----------
__global__ void gnn_prep(const float* __restrict__ xf,
                         unsigned short* __restrict__ xb,
                         unsigned char* __restrict__ ntype,
                         uint4* __restrict__ degz) {     // deg as uint4 (25K)
    int i = blockIdx.x * blockDim.x + threadIdx.x;
    if (i < 1600000) {                     // vec4 convert of x (6.4M floats)
        float4 v = reinterpret_cast<const float4*>(xf)[i];
        ushort4 o;
        o.x = f2bf(v.x); o.y = f2bf(v.y); o.z = f2bf(v.z); o.w = f2bf(v.w);
        reinterpret_cast<ushort4*>(xb)[i] = o;
        if ((i & 15) == 0)
            ntype[i >> 4] = (v.x == 0.0f) ? 0 : ((v.x == 1.0f) ? 1 : 2);
    } else if (i < 1625000) {
        degz[i - 1600000] = (uint4){0u, 0u, 0u, 0u};
    }
}

__device__ __forceinline__ bool edge_mask(int ntc, float a0) {
    if (ntc == 0) return a0 < 0.5f;
    if (ntc == 1) return a0 < 0.3f;
    return true;
}

// ---------- histogram of masked-edge degrees (also IS cnt) ----------
__global__ void gnn_hist(const int* __restrict__ eidx,
                         const float* __restrict__ ea,
                         const unsigned char* __restrict__ ntype,
                         int* __restrict__ deg) {
    int e = blockIdx.x * blockDim.x + threadIdx.x;
    if (e >= N_EDGES) return;
    int s = eidx[e];
    int d = eidx[N_EDGES + e];
    if (edge_mask(ntype[s], ea[e * 3])) atomicAdd(&deg[d], 1);
}

// ---------- 3-phase exclusive scan of deg[100K] ----------
__global__ void gnn_scanA(const int* __restrict__ deg,
                          int* __restrict__ tmp, int* __restrict__ bsum) {
    __shared__ int s[256];
    int i = blockIdx.x * 256 + threadIdx.x;
    int v = (i < N_NODES) ? deg[i] : 0;
    s[threadIdx.x] = v;
    for (int o = 1; o < 256; o <<= 1) {
        __syncthreads();
        int u = (threadIdx.x >= o) ? s[threadIdx.x - o] : 0;
        __syncthreads();
        s[threadIdx.x] += u;
    }
    __syncthreads();
    if (i < N_NODES) tmp[i] = s[threadIdx.x];          // inclusive
    if (threadIdx.x == 255) bsum[blockIdx.x] = s[255];
}
__global__ void gnn_scanB(const int* __restrict__ bsum, int* __restrict__ boff,
                          int nblk) {
    __shared__ int s[512];
    int t = threadIdx.x;
    int v = (t < nblk) ? bsum[t] : 0;
    s[t] = v;
    for (int o = 1; o < 512; o <<= 1) {
        __syncthreads();
        int u = (t >= o) ? s[t - o] : 0;
        __syncthreads();
        s[t] += u;
    }
    __syncthreads();
    if (t < nblk) boff[t] = s[t] - v;                  // exclusive
}
__global__ void gnn_scanC(const int* __restrict__ tmp, const int* __restrict__ deg,
                          const int* __restrict__ boff, int* __restrict__ off) {
    int i = blockIdx.x * 256 + threadIdx.x;
    if (i < N_NODES) off[i] = tmp[i] - deg[i] + boff[blockIdx.x];  // exclusive
}

// ---------- scatter: masked edges -> packed 8B records sorted by dst ----
// rec.x = src | a0q<<17 | (a1q&31)<<27 ; rec.y = dst | (a1q>>5)<<17 | a2q<<22
// (10-bit fixed-point attrs; mask already applied in exact fp32)
// off[] is consumed destructively: afterwards off[d] = inclusive end of d's run.
__global__ void gnn_scatter(const int* __restrict__ eidx,
                            const float* __restrict__ ea,
                            const unsigned char* __restrict__ ntype,
                            int* __restrict__ off,
                            uint2* __restrict__ rec) {
    int e = blockIdx.x * blockDim.x + threadIdx.x;
    if (e >= N_EDGES) return;
    int s = eidx[e];
    int d = eidx[N_EDGES + e];
    float a0 = ea[e * 3], a1 = ea[e * 3 + 1], a2 = ea[e * 3 + 2];
    if (!edge_mask(ntype[s], a0)) return;
    int pos = atomicAdd(&off[d], 1);
    unsigned a0q = (unsigned)(a0 * 1023.0f + 0.5f);
    unsigned a1q = (unsigned)(a1 * 1023.0f + 0.5f);
    unsigned a2q = (unsigned)(a2 * 1023.0f + 0.5f);
    uint2 r;
    r.x = (unsigned)s | (a0q << 17) | ((a1q & 31u) << 27);
    r.y = (unsigned)d | ((a1q >> 5) << 17) | (a2q << 22);
    rec[pos] = r;
}

// ---------- edge kernel over dst-sorted records ----------
// Block b owns nodes [b*100, b*100+100) and their contiguous edge run.
// Layer-1 MFMA as before; relu'd hidden accumulates into per-block LDS
// (ds_add_f32, stride-68 pad), then ONE coalesced f16 store per node row.
// No global atomics at all.
__global__ __launch_bounds__(256) void gnn_edge_sorted(
    const unsigned short* __restrict__ xb,    // [N_NODES][64] bf16 bits
    const uint2*          __restrict__ rec,   // sorted packed edges
    const int*            __restrict__ off,   // post-scatter: inclusive ends
    const float*          __restrict__ W1,    // [131][64]
    const float*          __restrict__ b1,    // [64]
    unsigned int*         __restrict__ hsumU) // [N_NODES][32] f16 pairs
{
    __shared__ __align__(16) unsigned short W1T[64][136];
    __shared__ float w1tail[4][64];
    __shared__ float hloc[NPB * 68];          // 27.2KB, +4 pad vs 64
    __shared__ float eas[128][4];
    __shared__ int   srcs[128];
    __shared__ int   dabs[128];               // clamped absolute dst node
    __shared__ int   dlocA[128];              // dst-nodeBase, -1 = invalid row

    const int tid  = threadIdx.x;
    const int wave = tid >> 6;
    const int lane = tid & 63;
    const int q    = lane >> 4;
    const int m16  = lane & 15;

    for (int idx = tid; idx < 128 * 64; idx += 256) {
        int k = idx >> 6, n = idx & 63;
        W1T[n][k] = f2bf(W1[idx]);
    }
    if (tid < 64) {
        w1tail[0][tid] = W1[128 * 64 + tid];
        w1tail[1][tid] = W1[129 * 64 + tid];
        w1tail[2][tid] = W1[130 * 64 + tid];
        w1tail[3][tid] = b1[tid];
    }
    for (int idx = tid; idx < NPB * 68; idx += 256) hloc[idx] = 0.0f;

    const int nodeBase = blockIdx.x * NPB;
    const int eStart = (nodeBase == 0) ? 0 : off[nodeBase - 1];
    const int eEnd   = off[nodeBase + NPB - 1];
    __syncthreads();

    for (int te = eStart; te < eEnd; te += 128) {
        if (tid < 128) {
            int e = te + tid;
            if (e < eEnd) {
                uint2 r = rec[e];
                int s = (int)(r.x & 0x1FFFFu);
                int d = (int)(r.y & 0x1FFFFu);
                srcs[tid]  = s;
                dabs[tid]  = d;
                dlocA[tid] = d - nodeBase;
                const float dq = 1.0f / 1023.0f;
                eas[tid][0] = (float)((r.x >> 17) & 1023u) * dq;
                eas[tid][1] = (float)(((r.x >> 27) & 31u) | (((r.y >> 17) & 31u) << 5)) * dq;
                eas[tid][2] = (float)((r.y >> 22) & 1023u) * dq;
            } else {
                srcs[tid] = 0; dabs[tid] = 0; dlocA[tid] = -1;
                eas[tid][0] = 0.f; eas[tid][1] = 0.f; eas[tid][2] = 0.f;
            }
        }
        __syncthreads();

        const int ebase = wave * 32;

        // acc init: b1 + ea @ W1[128:131]
        f32x4 acc1[2][4];
#pragma unroll
        for (int mt = 0; mt < 2; ++mt) {
            float e0[4], e1[4], e2[4];
#pragma unroll
            for (int r = 0; r < 4; ++r) {
                int el = ebase + mt * 16 + q * 4 + r;
                e0[r] = eas[el][0]; e1[r] = eas[el][1]; e2[r] = eas[el][2];
            }
#pragma unroll
            for (int nt = 0; nt < 4; ++nt) {
                int n = nt * 16 + m16;
                float t0 = w1tail[0][n], t1 = w1tail[1][n];
                float t2 = w1tail[2][n], bb = w1tail[3][n];
#pragma unroll
                for (int r = 0; r < 4; ++r)
                    acc1[mt][nt][r] = bb + e0[r] * t0 + e1[r] * t1 + e2[r] * t2;
            }
        }

        // K=128 over [x_dst | x_src]; dst loads are broadcast-heavy (sorted)
#pragma unroll
        for (int kc = 0; kc < 4; ++kc) {
            bf16x8 af[2];
#pragma unroll
            for (int mt = 0; mt < 2; ++mt) {
                int el   = ebase + mt * 16 + m16;
                int node = (kc < 2) ? dabs[el] : srcs[el];
                af[mt] = *reinterpret_cast<const bf16x8*>(
                    xb + (size_t)node * IN_CH + (kc & 1) * 32 + q * 8);
            }
#pragma unroll
            for (int nt = 0; nt < 4; ++nt) {
                bf16x8 bfr = *reinterpret_cast<const bf16x8*>(
                    &W1T[nt * 16 + m16][kc * 32 + q * 8]);
                acc1[0][nt] = __builtin_amdgcn_mfma_f32_16x16x32_bf16(af[0], bfr, acc1[0][nt], 0, 0, 0);
                acc1[1][nt] = __builtin_amdgcn_mfma_f32_16x16x32_bf16(af[1], bfr, acc1[1][nt], 0, 0, 0);
            }
        }

        // relu -> LDS segmented accumulate (ds_add_f32), zero-skip
#pragma unroll
        for (int mt = 0; mt < 2; ++mt) {
#pragma unroll
            for (int r = 0; r < 4; ++r) {
                int el = ebase + mt * 16 + q * 4 + r;
                int dl = dlocA[el];
                if (dl >= 0) {
                    float* hr = &hloc[dl * 68 + m16];
#pragma unroll
                    for (int nt = 0; nt < 4; ++nt) {
                        float v = acc1[mt][nt][r];
                        if (v > 0.0f) atomicAdd(&hr[nt * 16], v);
                    }
                }
            }
        }
        __syncthreads();   // protect eas/srcs staging for next tile
    }

    __syncthreads();
    // write node rows once: fp32 LDS -> packed f16 pairs, coalesced
    for (int idx = tid; idx < NPB * 32; idx += 256) {
        int ln = idx >> 5, c2 = idx & 31;
        f16x2 p = {(_Float16)hloc[ln * 68 + c2 * 2],
                   (_Float16)hloc[ln * 68 + c2 * 2 + 1]};
        union { f16x2 v; unsigned u; } cv; cv.v = p;
        hsumU[(size_t)(nodeBase + ln) * 32 + c2] = cv.u;
    }
}

// ---------- node kernel: out = relu(hsum @ W2 + deg*b2), MFMA ----------
__global__ __launch_bounds__(256, 4) void gnn_node_out(
    const _Float16* __restrict__ hsum,  // [N_NODES][64] f16
    const int*      __restrict__ deg,   // [N_NODES] masked-edge counts
    const float*    __restrict__ W2,    // [64][128]
    const float*    __restrict__ b2,    // [128]
    float*          __restrict__ out)   // [N_NODES][128]
{
    __shared__ __align__(16) unsigned short W2T[128][72];
    __shared__ float b2s[128];

    const int tid  = threadIdx.x;
    const int wave = tid >> 6;
    const int lane = tid & 63;
    const int q    = lane >> 4;
    const int m16  = lane & 15;

    for (int idx = tid; idx < 64 * 128; idx += 256) {
        int k = idx >> 7, n = idx & 127;
        W2T[n][k] = f2bf(W2[k * 128 + n]);
    }
    if (tid < 128) b2s[tid] = b2[tid];
    __syncthreads();

    const int nodeBase = (blockIdx.x * 4 + wave) * 32;
    if (nodeBase >= N_NODES) return;

    f32x4 acc[2][8];
#pragma unroll
    for (int mt = 0; mt < 2; ++mt)
#pragma unroll
        for (int nt = 0; nt < 8; ++nt)
            acc[mt][nt] = (f32x4){0.0f, 0.0f, 0.0f, 0.0f};

#pragma unroll
    for (int kc = 0; kc < 2; ++kc) {
        bf16x8 af[2];
#pragma unroll
        for (int mt = 0; mt < 2; ++mt) {
            int node = nodeBase + mt * 16 + m16;
            if (node >= N_NODES) node = N_NODES - 1;
            f16x8 h = *reinterpret_cast<const f16x8*>(
                hsum + (size_t)node * HID_CH + kc * 32 + q * 8);
            union { bf16x8 v; unsigned short u[8]; } rr;
#pragma unroll
            for (int j = 0; j < 8; ++j) rr.u[j] = f2bf((float)h[j]);
            af[mt] = rr.v;
        }
#pragma unroll
        for (int nt = 0; nt < 8; ++nt) {
            bf16x8 bfr = *reinterpret_cast<const bf16x8*>(
                &W2T[nt * 16 + m16][kc * 32 + q * 8]);
            acc[0][nt] = __builtin_amdgcn_mfma_f32_16x16x32_bf16(af[0], bfr, acc[0][nt], 0, 0, 0);
            acc[1][nt] = __builtin_amdgcn_mfma_f32_16x16x32_bf16(af[1], bfr, acc[1][nt], 0, 0, 0);
        }
    }

#pragma unroll
    for (int mt = 0; mt < 2; ++mt) {
        float cc[4]; int nn[4];
#pragma unroll
        for (int r = 0; r < 4; ++r) {
            nn[r] = nodeBase + mt * 16 + q * 4 + r;
            cc[r] = (nn[r] < N_NODES) ? (float)deg[nn[r]] : 0.0f;
        }
#pragma unroll
        for (int nt = 0; nt < 8; ++nt) {
            int col = nt * 16 + m16;
            float bb = b2s[col];
#pragma unroll
            for (int r = 0; r < 4; ++r) {
                if (nn[r] < N_NODES) {
                    float v = acc[mt][nt][r] + cc[r] * bb;
                    out[(size_t)nn[r] * OUT_CH + col] = v > 0.0f ? v : 0.0f;
                }
            }
        }
    }
}

extern "C" void kernel_launch(void* const* d_in, const int* in_sizes, int n_in,
                              void* d_out, int out_size, void* d_ws, size_t ws_size,
                              hipStream_t stream) {
    const float* x  = (const float*)d_in[0];
    const int*   ei = (const int*)d_in[1];
    const float* ea = (const float*)d_in[2];
    const float* W1 = (const float*)d_in[3];
    const float* b1 = (const float*)d_in[4];
    const float* W2 = (const float*)d_in[5];
    const float* b2 = (const float*)d_in[6];
    float* out = (float*)d_out;

    // ws layout (bytes, 64-aligned):
    // xb 0..12.8M | ntype @12.8M (100K) | deg @12,902,400 (400K)
    // off @13,302,400 (400K) | tmp @13,702,400 (400K) | bsum @14,102,400 (2K)
    // boff @14,104,448 (2K) | hsum @14,106,496 (12.8M) | rec @26,906,496 (12.8M)
    char* wsb = (char*)d_ws;
    unsigned short* xb    = (unsigned short*)(wsb);
    unsigned char*  ntype = (unsigned char*)(wsb + 12800000);
    int*            deg   = (int*)(wsb + 12902400);
    int*            off   = (int*)(wsb + 13302400);
    int*            tmp   = (int*)(wsb + 13702400);
    int*            bsum  = (int*)(wsb + 14102400);
    int*            boff  = (int*)(wsb + 14104448);
    unsigned int*   hsumU = (unsigned int*)(wsb + 14106496);
    uint2*          rec   = (uint2*)(wsb + 26906496);

    const int nScanBlk = (N_NODES + 255) / 256;   // 391

    gnn_prep<<<(1625000 + 255) / 256, 256, 0, stream>>>(
        x, xb, ntype, (uint4*)deg);
    gnn_hist<<<(N_EDGES + 255) / 256, 256, 0, stream>>>(ei, ea, ntype, deg);
    gnn_scanA<<<nScanBlk, 256, 0, stream>>>(deg, tmp, bsum);
    gnn_scanB<<<1, 512, 0, stream>>>(bsum, boff, nScanBlk);
    gnn_scanC<<<nScanBlk, 256, 0, stream>>>(tmp, deg, boff, off);
    gnn_scatter<<<(N_EDGES + 255) / 256, 256, 0, stream>>>(ei, ea, ntype, off, rec);
    gnn_edge_sorted<<<N_NODES / NPB, 256, 0, stream>>>(xb, rec, off, W1, b1, hsumU);
    gnn_node_out<<<(N_NODES + 127) / 128, 256, 0, stream>>>(
        (const _Float16*)hsumU, deg, W2, b2, out);
}

// Round 8
// 313.579 us; speedup vs baseline: 1.2975x; 1.2975x over previous
//
#include <hip/hip_runtime.h>

#define N_NODES 100000
#define N_EDGES 1600000
#define IN_CH   64
#define HID_CH  64
#define OUT_CH  128
#define TILE    128
#define N_TILES (N_EDGES / TILE)   // 12500 exactly

typedef __attribute__((ext_vector_type(8))) __bf16    bf16x8;
typedef __attribute__((ext_vector_type(4))) float     f32x4;
typedef __attribute__((ext_vector_type(2))) _Float16  f16x2;
typedef __attribute__((ext_vector_type(8))) _Float16  f16x8;

// Barrier WITHOUT vmcnt drain: __syncthreads() emits s_waitcnt vmcnt(0)
// lgkmcnt(0) before s_barrier, draining the fire-and-forget atomic queue and
// gather pipeline every tile (the R6 stall). LDS staging only needs lgkmcnt.
#define LGKM_BARRIER() asm volatile("s_waitcnt lgkmcnt(0)\n\ts_barrier" ::: "memory")

__device__ __forceinline__ unsigned short f2bf(float f) {
    union { float f; unsigned int i; } c;
    c.f = f;
    unsigned int u = c.i;
    unsigned int r = (u + 0x7FFFu + ((u >> 16) & 1u)) >> 16;   // RNE
    return (unsigned short)r;
}

// packed fp16 atomic add (global_atomic_pk_add_f16, gfx90a+)
__device__ __forceinline__ void atomic_pk_add_f16(unsigned int* addr, f16x2 val) {
    typedef __attribute__((address_space(1))) f16x2 gf16x2;
    __builtin_amdgcn_global_atomic_fadd_v2f16((gf16x2*)(void*)addr, val);
}

__device__ __forceinline__ float mask_of(int ntc, float a0) {
    if (ntc == 0) return (a0 < 0.5f) ? 1.0f : 0.0f;
    if (ntc == 1) return (a0 < 0.3f) ? 1.0f : 0.0f;
    return 1.0f;
}

// fused prep: x fp32->bf16 convert + node-type byte table + zero hsum/cnt.
__global__ void gnn_prep(const float* __restrict__ xf,
                         unsigned short* __restrict__ xb,
                         unsigned char* __restrict__ ntype,  // [N_NODES]
                         uint4* __restrict__ hz,      // hsum as uint4 (800k)
                         float4* __restrict__ cz) {   // cnt  as float4 (25k)
    int i = blockIdx.x * blockDim.x + threadIdx.x;
    if (i < 1600000) {
        float4 v = reinterpret_cast<const float4*>(xf)[i];
        ushort4 o;
        o.x = f2bf(v.x); o.y = f2bf(v.y); o.z = f2bf(v.z); o.w = f2bf(v.w);
        reinterpret_cast<ushort4*>(xb)[i] = o;
        if ((i & 15) == 0) {
            int n = i >> 4;
            ntype[n] = (v.x == 0.0f) ? 0 : ((v.x == 1.0f) ? 1 : 2);
        }
    } else if (i < 2400000) {
        hz[i - 1600000] = (uint4){0u, 0u, 0u, 0u};
    } else if (i < 2425000) {
        cz[i - 2400000] = (float4){0.f, 0.f, 0.f, 0.f};
    }
}

// Edge kernel (R6 structure + lgkm-only barriers + double-buffered staging):
// h_e = relu([x_dst|x_src|ea] @ W1 + b1); masked scatter of the 64-ch hidden
// into hsum[dst] as packed fp16 atomics (2 ch/dword), zero-pair skip.
// hsum channel order permuted (dword d<16 -> ch (d,d+16); d>=16 ->
// (d+16,d+32)); node kernel permutes W2's rows identically.
// One lgkm-only barrier per tile; next-tile staging loads issue before the
// compute section so gather/atomic traffic overlaps across tiles.
__global__ __launch_bounds__(256, 6) void gnn_edge_hidden(
    const unsigned char*  __restrict__ ntype, // [N_NODES] node type 0/1/2
    const unsigned short* __restrict__ xb,    // [N_NODES][64] bf16 bits
    const int*            __restrict__ eidx,  // [2][N_EDGES]
    const float*          __restrict__ ea,    // [N_EDGES][3]
    const float*          __restrict__ W1,    // [131][64]
    const float*          __restrict__ b1,    // [64]
    unsigned int*         __restrict__ hsum,  // [N_NODES][32] packed-f16 pairs
    float*                __restrict__ cnt)   // [N_NODES] masked-edge counts
{
    __shared__ __align__(16) unsigned short W1T[64][136];   // W1T[n][k]=W1[k][n]
    __shared__ float w1tail[4][64];   // W1[128..130], b1 (fp32)
    __shared__ float eas[2][128][4];  // double-buffered staging
    __shared__ float masks[2][128];
    __shared__ int   dsts[2][128];
    __shared__ int   srcs[2][128];

    const int tid  = threadIdx.x;
    const int wave = tid >> 6;
    const int lane = tid & 63;
    const int q    = lane >> 4;   // quad 0..3
    const int m16  = lane & 15;

    // ---- stage W1 once per persistent block (fp32 -> bf16) ----
    for (int idx = tid; idx < 128 * 64; idx += 256) {
        int k = idx >> 6, n = idx & 63;
        W1T[n][k] = f2bf(W1[idx]);
    }
    if (tid < 64) {
        w1tail[0][tid] = W1[128 * 64 + tid];
        w1tail[1][tid] = W1[129 * 64 + tid];
        w1tail[2][tid] = W1[130 * 64 + tid];
        w1tail[3][tid] = b1[tid];
    }

    const int stride = gridDim.x;
    int t = blockIdx.x;

    // prologue: stage first tile into buffer 0
    if (tid < 128) {
        int e = t * TILE + tid;
        int s = eidx[e];
        int d = eidx[N_EDGES + e];
        float a0 = ea[e * 3 + 0];
        float a1 = ea[e * 3 + 1];
        float a2 = ea[e * 3 + 2];
        int ntc = ntype[s];
        srcs[0][tid] = s; dsts[0][tid] = d;
        eas[0][tid][0] = a0; eas[0][tid][1] = a1; eas[0][tid][2] = a2;
        float mk = mask_of(ntc, a0);
        masks[0][tid] = mk;
        if (mk != 0.0f) unsafeAtomicAdd(&cnt[d], 1.0f);
    }
    LGKM_BARRIER();

    int p = 0;
    while (t < N_TILES) {
        const int tn = t + stride;
        const bool doStage = (tn < N_TILES) && (tid < 128);

        // issue next-tile staging loads EARLY (latency hidden under compute)
        int sN = 0, dN = 0, ntN = 2;
        float a0N = 0.f, a1N = 0.f, a2N = 0.f;
        if (doStage) {
            int e = tn * TILE + tid;
            sN  = eidx[e];
            dN  = eidx[N_EDGES + e];
            a0N = ea[e * 3 + 0];
            a1N = ea[e * 3 + 1];
            a2N = ea[e * 3 + 2];
            ntN = ntype[sN];
        }

        const int ebase = wave * 32;

        // ---- acc init: b1 + ea @ W1[128:131] (fp32 VALU) ----
        f32x4 acc1[2][4];
#pragma unroll
        for (int mt = 0; mt < 2; ++mt) {
            float e0[4], e1[4], e2[4];
#pragma unroll
            for (int r = 0; r < 4; ++r) {
                int el = ebase + mt * 16 + q * 4 + r;   // C-layout row
                e0[r] = eas[p][el][0]; e1[r] = eas[p][el][1]; e2[r] = eas[p][el][2];
            }
#pragma unroll
            for (int nt = 0; nt < 4; ++nt) {
                int n = nt * 16 + m16;                  // C-layout col
                float t0 = w1tail[0][n], t1 = w1tail[1][n];
                float t2 = w1tail[2][n], bb = w1tail[3][n];
#pragma unroll
                for (int r = 0; r < 4; ++r)
                    acc1[mt][nt][r] = bb + e0[r] * t0 + e1[r] * t1 + e2[r] * t2;
            }
        }

        // K=128 over [x_dst (kc 0,1) | x_src (kc 2,3)], A-frags from global bf16
#pragma unroll
        for (int kc = 0; kc < 4; ++kc) {
            bf16x8 af[2];
#pragma unroll
            for (int mt = 0; mt < 2; ++mt) {
                int el   = ebase + mt * 16 + m16;       // A-layout row m=lane&15
                int node = (kc < 2) ? dsts[p][el] : srcs[p][el];
                af[mt] = *reinterpret_cast<const bf16x8*>(
                    xb + (size_t)node * IN_CH + (kc & 1) * 32 + q * 8);
            }
#pragma unroll
            for (int nt = 0; nt < 4; ++nt) {
                bf16x8 bfr = *reinterpret_cast<const bf16x8*>(
                    &W1T[nt * 16 + m16][kc * 32 + q * 8]);
                acc1[0][nt] = __builtin_amdgcn_mfma_f32_16x16x32_bf16(af[0], bfr, acc1[0][nt], 0, 0, 0);
                acc1[1][nt] = __builtin_amdgcn_mfma_f32_16x16x32_bf16(af[1], bfr, acc1[1][nt], 0, 0, 0);
            }
        }

        // ---- epilogue: masked relu(h) -> packed fp16 atomics, zero-skip ----
#pragma unroll
        for (int mt = 0; mt < 2; ++mt) {
#pragma unroll
            for (int r = 0; r < 4; ++r) {
                int el = ebase + mt * 16 + q * 4 + r;   // C-layout row
                float mk = masks[p][el];
                if (mk != 0.0f) {
                    unsigned int* hbase = hsum + (size_t)dsts[p][el] * 32;
                    float v0 = acc1[mt][0][r]; v0 = v0 > 0.f ? v0 : 0.f;
                    float v1 = acc1[mt][1][r]; v1 = v1 > 0.f ? v1 : 0.f;
                    float v2 = acc1[mt][2][r]; v2 = v2 > 0.f ? v2 : 0.f;
                    float v3 = acc1[mt][3][r]; v3 = v3 > 0.f ? v3 : 0.f;
                    if (v0 + v1 > 0.f) {   // pair (m16, m16+16) -> dword m16
                        f16x2 p01 = {(_Float16)v0, (_Float16)v1};
                        atomic_pk_add_f16(hbase + m16, p01);
                    }
                    if (v2 + v3 > 0.f) {   // pair (m16+32, m16+48) -> dword 16+m16
                        f16x2 p23 = {(_Float16)v2, (_Float16)v3};
                        atomic_pk_add_f16(hbase + 16 + m16, p23);
                    }
                }
            }
        }

        // ---- write next-tile staging into the other buffer ----
        if (doStage) {
            srcs[p ^ 1][tid] = sN; dsts[p ^ 1][tid] = dN;
            eas[p ^ 1][tid][0] = a0N; eas[p ^ 1][tid][1] = a1N; eas[p ^ 1][tid][2] = a2N;
            float mk = mask_of(ntN, a0N);
            masks[p ^ 1][tid] = mk;
            if (mk != 0.0f) unsafeAtomicAdd(&cnt[dN], 1.0f);
        }
        LGKM_BARRIER();   // lgkm only: atomics/gathers stay in flight
        p ^= 1;
        t = tn;
    }
}

// Node kernel (MFMA): out[n] = relu(hsum[n] @ W2 + cnt[n]*b2).
// hsum is fp16 in permuted channel order pi(p); W2's rows staged likewise.
__global__ __launch_bounds__(256, 4) void gnn_node_out(
    const _Float16* __restrict__ hsum,  // [N_NODES][64] fp16, permuted channels
    const float*    __restrict__ cnt,   // [N_NODES]
    const float*    __restrict__ W2,    // [64][128]
    const float*    __restrict__ b2,    // [128]
    float*          __restrict__ out)   // [N_NODES][128]
{
    __shared__ __align__(16) unsigned short W2T[128][72];  // W2T[n][p]=W2[pi(p)][n]
    __shared__ float b2s[128];

    const int tid  = threadIdx.x;
    const int wave = tid >> 6;
    const int lane = tid & 63;
    const int q    = lane >> 4;
    const int m16  = lane & 15;

    for (int idx = tid; idx < 64 * 128; idx += 256) {
        int p = idx >> 7, n = idx & 127;
        // pi(p): dword d=p>>1, half e=p&1; d<16 -> ch d+16e; d>=16 -> ch d+16+16e
        int ch = (p >> 1) + 16 * (p & 1) + ((p >= 32) ? 16 : 0);
        W2T[n][p] = f2bf(W2[ch * 128 + n]);
    }
    if (tid < 128) b2s[tid] = b2[tid];
    __syncthreads();

    const int nodeBase = (blockIdx.x * 4 + wave) * 32;
    if (nodeBase >= N_NODES) return;   // tail waves (no barriers below)

    f32x4 acc[2][8];
#pragma unroll
    for (int mt = 0; mt < 2; ++mt)
#pragma unroll
        for (int nt = 0; nt < 8; ++nt)
            acc[mt][nt] = (f32x4){0.0f, 0.0f, 0.0f, 0.0f};

#pragma unroll
    for (int kc = 0; kc < 2; ++kc) {
        bf16x8 af[2];
#pragma unroll
        for (int mt = 0; mt < 2; ++mt) {
            int node = nodeBase + mt * 16 + m16;       // A-layout row
            if (node >= N_NODES) node = N_NODES - 1;   // clamp; rows unused
            f16x8 h = *reinterpret_cast<const f16x8*>(
                hsum + (size_t)node * HID_CH + kc * 32 + q * 8);
            union { bf16x8 v; unsigned short u[8]; } rr;
#pragma unroll
            for (int j = 0; j < 8; ++j) rr.u[j] = f2bf((float)h[j]);
            af[mt] = rr.v;
        }
#pragma unroll
        for (int nt = 0; nt < 8; ++nt) {
            bf16x8 bfr = *reinterpret_cast<const bf16x8*>(
                &W2T[nt * 16 + m16][kc * 32 + q * 8]);
            acc[0][nt] = __builtin_amdgcn_mfma_f32_16x16x32_bf16(af[0], bfr, acc[0][nt], 0, 0, 0);
            acc[1][nt] = __builtin_amdgcn_mfma_f32_16x16x32_bf16(af[1], bfr, acc[1][nt], 0, 0, 0);
        }
    }

    // epilogue: + cnt*b2, relu, store (C-layout: row=q*4+r, col=nt*16+m16)
#pragma unroll
    for (int mt = 0; mt < 2; ++mt) {
        float cc[4]; int nn[4];
#pragma unroll
        for (int r = 0; r < 4; ++r) {
            nn[r] = nodeBase + mt * 16 + q * 4 + r;
            cc[r] = (nn[r] < N_NODES) ? cnt[nn[r]] : 0.0f;
        }
#pragma unroll
        for (int nt = 0; nt < 8; ++nt) {
            int col = nt * 16 + m16;
            float bb = b2s[col];
#pragma unroll
            for (int r = 0; r < 4; ++r) {
                if (nn[r] < N_NODES) {
                    float v = acc[mt][nt][r] + cc[r] * bb;
                    out[(size_t)nn[r] * OUT_CH + col] = v > 0.0f ? v : 0.0f;
                }
            }
        }
    }
}

extern "C" void kernel_launch(void* const* d_in, const int* in_sizes, int n_in,
                              void* d_out, int out_size, void* d_ws, size_t ws_size,
                              hipStream_t stream) {
    const float* x  = (const float*)d_in[0];
    const int*   ei = (const int*)d_in[1];
    const float* ea = (const float*)d_in[2];
    const float* W1 = (const float*)d_in[3];
    const float* b1 = (const float*)d_in[4];
    const float* W2 = (const float*)d_in[5];
    const float* b2 = (const float*)d_in[6];
    float* out = (float*)d_out;

    // ws layout: [hsum fp16 12.8MB][cnt 0.4MB][xb bf16 12.8MB][ntype 0.1MB]
    char* wsb = (char*)d_ws;
    unsigned int*   hsum  = (unsigned int*)wsb;                   // packed pairs
    float*          cnt   = (float*)(wsb + 12800000);
    unsigned short* xb    = (unsigned short*)(wsb + 13200000);
    unsigned char*  ntype = (unsigned char*)(wsb + 26000000);

    // fused prep: x->bf16 + node-type table + zero hsum/cnt
    gnn_prep<<<(2425000 + 255) / 256, 256, 0, stream>>>(
        x, xb, ntype, (uint4*)hsum, (float4*)cnt);

    // 1536 blocks = 6 blocks/CU (25.6KB LDS) — layer 1 + pk-f16 scatter
    gnn_edge_hidden<<<1536, 256, 0, stream>>>(ntype, xb, ei, ea, W1, b1, hsum, cnt);

    // node-level layer 2 + relu via MFMA: 128 nodes/block, 782 blocks
    gnn_node_out<<<(N_NODES + 127) / 128, 256, 0, stream>>>(
        (const _Float16*)hsum, cnt, W2, b2, out);
}

// Round 9
// 300.281 us; speedup vs baseline: 1.3549x; 1.0443x over previous
//
#include <hip/hip_runtime.h>

#define N_NODES 100000
#define N_EDGES 1600000
#define IN_CH   64
#define HID_CH  64
#define OUT_CH  128

typedef __attribute__((ext_vector_type(8))) __bf16    bf16x8;
typedef __attribute__((ext_vector_type(4))) float     f32x4;
typedef __attribute__((ext_vector_type(2))) _Float16  f16x2;
typedef __attribute__((ext_vector_type(8))) _Float16  f16x8;

__device__ __forceinline__ unsigned short f2bf(float f) {
    union { float f; unsigned int i; } c;
    c.f = f;
    unsigned int u = c.i;
    unsigned int r = (u + 0x7FFFu + ((u >> 16) & 1u)) >> 16;   // RNE
    return (unsigned short)r;
}

// packed fp16 atomic add (global_atomic_pk_add_f16)
__device__ __forceinline__ void atomic_pk_add_f16(unsigned int* addr, f16x2 val) {
    typedef __attribute__((address_space(1))) f16x2 gf16x2;
    __builtin_amdgcn_global_atomic_fadd_v2f16((gf16x2*)(void*)addr, val);
}

__device__ __forceinline__ bool edge_mask(int ntc, float a0) {
    if (ntc == 0) return a0 < 0.5f;
    if (ntc == 1) return a0 < 0.3f;
    return true;
}

// ---------- prep: x fp32->bf16 + ntype table + zero hsum/deg ----------
__global__ void gnn_prep(const float* __restrict__ xf,
                         unsigned short* __restrict__ xb,
                         unsigned char* __restrict__ ntype,
                         uint4* __restrict__ hz,      // hsum zero (800K uint4)
                         uint4* __restrict__ dz) {    // deg  zero (25K uint4)
    int i = blockIdx.x * blockDim.x + threadIdx.x;
    if (i < 1600000) {
        float4 v = reinterpret_cast<const float4*>(xf)[i];
        ushort4 o;
        o.x = f2bf(v.x); o.y = f2bf(v.y); o.z = f2bf(v.z); o.w = f2bf(v.w);
        reinterpret_cast<ushort4*>(xb)[i] = o;
        if ((i & 15) == 0)
            ntype[i >> 4] = (v.x == 0.0f) ? 0 : ((v.x == 1.0f) ? 1 : 2);
    } else if (i < 2400000) {
        hz[i - 1600000] = (uint4){0u, 0u, 0u, 0u};
    } else if (i < 2425000) {
        dz[i - 2400000] = (uint4){0u, 0u, 0u, 0u};
    }
}

// ---------- histogram of masked-edge degrees (also IS cnt for b2) ----------
__global__ void gnn_hist(const int* __restrict__ eidx,
                         const float* __restrict__ ea,
                         const unsigned char* __restrict__ ntype,
                         int* __restrict__ deg) {
    int e = blockIdx.x * blockDim.x + threadIdx.x;
    if (e >= N_EDGES) return;
    int s = eidx[e];
    int d = eidx[N_EDGES + e];
    if (edge_mask(ntype[s], ea[e * 3])) atomicAdd(&deg[d], 1);
}

// ---------- 3-phase exclusive scan of deg[100K] (verified R7) ----------
__global__ void gnn_scanA(const int* __restrict__ deg,
                          int* __restrict__ tmp, int* __restrict__ bsum) {
    __shared__ int s[256];
    int i = blockIdx.x * 256 + threadIdx.x;
    int v = (i < N_NODES) ? deg[i] : 0;
    s[threadIdx.x] = v;
    for (int o = 1; o < 256; o <<= 1) {
        __syncthreads();
        int u = (threadIdx.x >= o) ? s[threadIdx.x - o] : 0;
        __syncthreads();
        s[threadIdx.x] += u;
    }
    __syncthreads();
    if (i < N_NODES) tmp[i] = s[threadIdx.x];          // inclusive
    if (threadIdx.x == 255) bsum[blockIdx.x] = s[255];
}
__global__ void gnn_scanB(const int* __restrict__ bsum, int* __restrict__ boff,
                          int nblk) {
    __shared__ int s[512];
    int t = threadIdx.x;
    int v = (t < nblk) ? bsum[t] : 0;
    s[t] = v;
    for (int o = 1; o < 512; o <<= 1) {
        __syncthreads();
        int u = (t >= o) ? s[t - o] : 0;
        __syncthreads();
        s[t] += u;
    }
    __syncthreads();
    if (t < nblk) boff[t] = s[t] - v;                  // exclusive
}
__global__ void gnn_scanC(const int* __restrict__ tmp, const int* __restrict__ deg,
                          const int* __restrict__ boff, int* __restrict__ off) {
    int i = blockIdx.x * 256 + threadIdx.x;
    if (i < N_NODES) off[i] = tmp[i] - deg[i] + boff[blockIdx.x];  // exclusive
}

// ---------- scatter: masked edges -> 8B records sorted by dst (R7) ----------
// rec.x = src | a0q<<17 | (a1q&31)<<27 ; rec.y = dst | (a1q>>5)<<17 | a2q<<22
// off[] consumed destructively: afterwards off[d] = inclusive end of d's run.
__global__ void gnn_scatter(const int* __restrict__ eidx,
                            const float* __restrict__ ea,
                            const unsigned char* __restrict__ ntype,
                            int* __restrict__ off,
                            uint2* __restrict__ rec) {
    int e = blockIdx.x * blockDim.x + threadIdx.x;
    if (e >= N_EDGES) return;
    int s = eidx[e];
    int d = eidx[N_EDGES + e];
    float a0 = ea[e * 3], a1 = ea[e * 3 + 1], a2 = ea[e * 3 + 2];
    if (!edge_mask(ntype[s], a0)) return;
    int pos = atomicAdd(&off[d], 1);
    unsigned a0q = (unsigned)(a0 * 1023.0f + 0.5f);
    unsigned a1q = (unsigned)(a1 * 1023.0f + 0.5f);
    unsigned a2q = (unsigned)(a2 * 1023.0f + 0.5f);
    uint2 r;
    r.x = (unsigned)s | (a0q << 17) | ((a1q & 31u) << 27);
    r.y = (unsigned)d | ((a1q >> 5) << 17) | (a2q << 22);
    rec[pos] = r;
}

// ---------- edge kernel: R6 engine over dst-sorted records ----------
// Grid-stride 128-record tiles, layer-1 MFMA, pk-f16 global atomics into
// hsum[dst]. Sorted stream => dst-frag gathers are L1 broadcasts, and the 4
// consecutive records in each quad's C-rows usually share dst => 4 atomics
// collapse to 1 (fp32-presummed). No LDS accumulation (R7's killer), plain
// __syncthreads (R8 showed loose sync spreads atomics and hurts combining).
__global__ __launch_bounds__(256, 4) void gnn_edge_sorted(
    const unsigned short* __restrict__ xb,    // [N_NODES][64] bf16 bits
    const uint2*          __restrict__ rec,   // sorted packed edges
    const int*            __restrict__ off,   // inclusive ends; off[N-1]=M
    const float*          __restrict__ W1,    // [131][64]
    const float*          __restrict__ b1,    // [64]
    unsigned int*         __restrict__ hsum)  // [N_NODES][32] f16 pairs
{
    __shared__ __align__(16) unsigned short W1T[64][136];
    __shared__ float w1tail[4][64];
    __shared__ float eas[128][4];
    __shared__ int   srcs[128];
    __shared__ int   dabs[128];    // dst or 0 (pad)
    __shared__ int   dsts[128];    // dst or -1 (pad)

    const int tid  = threadIdx.x;
    const int wave = tid >> 6;
    const int lane = tid & 63;
    const int q    = lane >> 4;
    const int m16  = lane & 15;

    for (int idx = tid; idx < 128 * 64; idx += 256) {
        int k = idx >> 6, n = idx & 63;
        W1T[n][k] = f2bf(W1[idx]);
    }
    if (tid < 64) {
        w1tail[0][tid] = W1[128 * 64 + tid];
        w1tail[1][tid] = W1[129 * 64 + tid];
        w1tail[2][tid] = W1[130 * 64 + tid];
        w1tail[3][tid] = b1[tid];
    }

    const int M      = off[N_NODES - 1];
    const int nTiles = (M + 127) >> 7;

    for (int t = blockIdx.x; t < nTiles; t += gridDim.x) {
        __syncthreads();   // LDS WAR (and 1st-iter weight staging)
        if (tid < 128) {
            int e = (t << 7) + tid;
            if (e < M) {
                uint2 r = rec[e];
                int s = (int)(r.x & 0x1FFFFu);
                int d = (int)(r.y & 0x1FFFFu);
                srcs[tid] = s; dabs[tid] = d; dsts[tid] = d;
                const float dq = 1.0f / 1023.0f;
                eas[tid][0] = (float)((r.x >> 17) & 1023u) * dq;
                eas[tid][1] = (float)(((r.x >> 27) & 31u) | (((r.y >> 17) & 31u) << 5)) * dq;
                eas[tid][2] = (float)((r.y >> 22) & 1023u) * dq;
            } else {
                srcs[tid] = 0; dabs[tid] = 0; dsts[tid] = -1;
                eas[tid][0] = 0.f; eas[tid][1] = 0.f; eas[tid][2] = 0.f;
            }
        }
        __syncthreads();

        const int ebase = wave * 32;

        // acc init: b1 + ea @ W1[128:131] (fp32 VALU)
        f32x4 acc1[2][4];
#pragma unroll
        for (int mt = 0; mt < 2; ++mt) {
            float e0[4], e1[4], e2[4];
#pragma unroll
            for (int r = 0; r < 4; ++r) {
                int el = ebase + mt * 16 + q * 4 + r;   // C-layout row
                e0[r] = eas[el][0]; e1[r] = eas[el][1]; e2[r] = eas[el][2];
            }
#pragma unroll
            for (int nt = 0; nt < 4; ++nt) {
                int n = nt * 16 + m16;                  // C-layout col
                float t0 = w1tail[0][n], t1 = w1tail[1][n];
                float t2 = w1tail[2][n], bb = w1tail[3][n];
#pragma unroll
                for (int r = 0; r < 4; ++r)
                    acc1[mt][nt][r] = bb + e0[r] * t0 + e1[r] * t1 + e2[r] * t2;
            }
        }

        // K=128 over [x_dst | x_src]; dst loads broadcast-heavy (sorted)
#pragma unroll
        for (int kc = 0; kc < 4; ++kc) {
            bf16x8 af[2];
#pragma unroll
            for (int mt = 0; mt < 2; ++mt) {
                int el   = ebase + mt * 16 + m16;       // A-layout row
                int node = (kc < 2) ? dabs[el] : srcs[el];
                af[mt] = *reinterpret_cast<const bf16x8*>(
                    xb + (size_t)node * IN_CH + (kc & 1) * 32 + q * 8);
            }
#pragma unroll
            for (int nt = 0; nt < 4; ++nt) {
                bf16x8 bfr = *reinterpret_cast<const bf16x8*>(
                    &W1T[nt * 16 + m16][kc * 32 + q * 8]);
                acc1[0][nt] = __builtin_amdgcn_mfma_f32_16x16x32_bf16(af[0], bfr, acc1[0][nt], 0, 0, 0);
                acc1[1][nt] = __builtin_amdgcn_mfma_f32_16x16x32_bf16(af[1], bfr, acc1[1][nt], 0, 0, 0);
            }
        }

        // epilogue: relu -> pk-f16 atomics with same-dst run combining.
        // hsum channel permutation pi: dword d<16 -> ch (d,d+16);
        // d>=16 -> ch (d+16,d+32). Node kernel stages W2 rows with same pi.
#pragma unroll
        for (int mt = 0; mt < 2; ++mt) {
            int dd[4];
            float v[4][4];
#pragma unroll
            for (int r = 0; r < 4; ++r)
                dd[r] = dsts[ebase + mt * 16 + q * 4 + r];
#pragma unroll
            for (int nt = 0; nt < 4; ++nt)
#pragma unroll
                for (int r = 0; r < 4; ++r) {
                    float w = acc1[mt][nt][r];
                    v[nt][r] = w > 0.0f ? w : 0.0f;
                }
            bool same = (dd[0] == dd[1]) && (dd[0] == dd[2]) && (dd[0] == dd[3]);
            if (same && dd[0] >= 0) {
                // 4 consecutive same-dst records: presum in fp32, 2 atomics
                unsigned int* hbase = hsum + (size_t)dd[0] * 32;
                float s0 = (v[0][0] + v[0][1]) + (v[0][2] + v[0][3]);
                float s1 = (v[1][0] + v[1][1]) + (v[1][2] + v[1][3]);
                float s2 = (v[2][0] + v[2][1]) + (v[2][2] + v[2][3]);
                float s3 = (v[3][0] + v[3][1]) + (v[3][2] + v[3][3]);
                if (s0 + s1 > 0.f)
                    atomic_pk_add_f16(hbase + m16, (f16x2){(_Float16)s0, (_Float16)s1});
                if (s2 + s3 > 0.f)
                    atomic_pk_add_f16(hbase + 16 + m16, (f16x2){(_Float16)s2, (_Float16)s3});
            } else {
#pragma unroll
                for (int r = 0; r < 4; ++r) {
                    if (dd[r] >= 0) {
                        unsigned int* hbase = hsum + (size_t)dd[r] * 32;
                        if (v[0][r] + v[1][r] > 0.f)
                            atomic_pk_add_f16(hbase + m16,
                                (f16x2){(_Float16)v[0][r], (_Float16)v[1][r]});
                        if (v[2][r] + v[3][r] > 0.f)
                            atomic_pk_add_f16(hbase + 16 + m16,
                                (f16x2){(_Float16)v[2][r], (_Float16)v[3][r]});
                    }
                }
            }
        }
    }
}

// ---------- node kernel: out = relu(hsum @ W2 + deg*b2), MFMA ----------
__global__ __launch_bounds__(256, 4) void gnn_node_out(
    const _Float16* __restrict__ hsum,  // [N_NODES][64] f16, permuted channels
    const int*      __restrict__ deg,   // [N_NODES]
    const float*    __restrict__ W2,    // [64][128]
    const float*    __restrict__ b2,    // [128]
    float*          __restrict__ out)   // [N_NODES][128]
{
    __shared__ __align__(16) unsigned short W2T[128][72];  // W2T[n][p]=W2[pi(p)][n]
    __shared__ float b2s[128];

    const int tid  = threadIdx.x;
    const int wave = tid >> 6;
    const int lane = tid & 63;
    const int q    = lane >> 4;
    const int m16  = lane & 15;

    for (int idx = tid; idx < 64 * 128; idx += 256) {
        int p = idx >> 7, n = idx & 127;
        // pi(p): dword d=p>>1, half e=p&1; d<16 -> ch d+16e; d>=16 -> d+16+16e
        int ch = (p >> 1) + 16 * (p & 1) + ((p >= 32) ? 16 : 0);
        W2T[n][p] = f2bf(W2[ch * 128 + n]);
    }
    if (tid < 128) b2s[tid] = b2[tid];
    __syncthreads();

    const int nodeBase = (blockIdx.x * 4 + wave) * 32;
    if (nodeBase >= N_NODES) return;

    f32x4 acc[2][8];
#pragma unroll
    for (int mt = 0; mt < 2; ++mt)
#pragma unroll
        for (int nt = 0; nt < 8; ++nt)
            acc[mt][nt] = (f32x4){0.0f, 0.0f, 0.0f, 0.0f};

#pragma unroll
    for (int kc = 0; kc < 2; ++kc) {
        bf16x8 af[2];
#pragma unroll
        for (int mt = 0; mt < 2; ++mt) {
            int node = nodeBase + mt * 16 + m16;
            if (node >= N_NODES) node = N_NODES - 1;
            f16x8 h = *reinterpret_cast<const f16x8*>(
                hsum + (size_t)node * HID_CH + kc * 32 + q * 8);
            union { bf16x8 v; unsigned short u[8]; } rr;
#pragma unroll
            for (int j = 0; j < 8; ++j) rr.u[j] = f2bf((float)h[j]);
            af[mt] = rr.v;
        }
#pragma unroll
        for (int nt = 0; nt < 8; ++nt) {
            bf16x8 bfr = *reinterpret_cast<const bf16x8*>(
                &W2T[nt * 16 + m16][kc * 32 + q * 8]);
            acc[0][nt] = __builtin_amdgcn_mfma_f32_16x16x32_bf16(af[0], bfr, acc[0][nt], 0, 0, 0);
            acc[1][nt] = __builtin_amdgcn_mfma_f32_16x16x32_bf16(af[1], bfr, acc[1][nt], 0, 0, 0);
        }
    }

#pragma unroll
    for (int mt = 0; mt < 2; ++mt) {
        float cc[4]; int nn[4];
#pragma unroll
        for (int r = 0; r < 4; ++r) {
            nn[r] = nodeBase + mt * 16 + q * 4 + r;
            cc[r] = (nn[r] < N_NODES) ? (float)deg[nn[r]] : 0.0f;
        }
#pragma unroll
        for (int nt = 0; nt < 8; ++nt) {
            int col = nt * 16 + m16;
            float bb = b2s[col];
#pragma unroll
            for (int r = 0; r < 4; ++r) {
                if (nn[r] < N_NODES) {
                    float v = acc[mt][nt][r] + cc[r] * bb;
                    out[(size_t)nn[r] * OUT_CH + col] = v > 0.0f ? v : 0.0f;
                }
            }
        }
    }
}

extern "C" void kernel_launch(void* const* d_in, const int* in_sizes, int n_in,
                              void* d_out, int out_size, void* d_ws, size_t ws_size,
                              hipStream_t stream) {
    const float* x  = (const float*)d_in[0];
    const int*   ei = (const int*)d_in[1];
    const float* ea = (const float*)d_in[2];
    const float* W1 = (const float*)d_in[3];
    const float* b1 = (const float*)d_in[4];
    const float* W2 = (const float*)d_in[5];
    const float* b2 = (const float*)d_in[6];
    float* out = (float*)d_out;

    // ws layout (bytes):
    // xb 0..12.8M | ntype @12.8M (100K) | deg @12,902,400 (400K)
    // off @13,302,400 | tmp @13,702,400 | bsum @14,102,400 | boff @14,104,448
    // hsum @14,106,496 (12.8M) | rec @26,906,496 (<=12.8M)
    char* wsb = (char*)d_ws;
    unsigned short* xb    = (unsigned short*)(wsb);
    unsigned char*  ntype = (unsigned char*)(wsb + 12800000);
    int*            deg   = (int*)(wsb + 12902400);
    int*            off   = (int*)(wsb + 13302400);
    int*            tmp   = (int*)(wsb + 13702400);
    int*            bsum  = (int*)(wsb + 14102400);
    int*            boff  = (int*)(wsb + 14104448);
    unsigned int*   hsumU = (unsigned int*)(wsb + 14106496);
    uint2*          rec   = (uint2*)(wsb + 26906496);

    const int nScanBlk = (N_NODES + 255) / 256;   // 391

    gnn_prep<<<(2425000 + 255) / 256, 256, 0, stream>>>(
        x, xb, ntype, (uint4*)hsumU, (uint4*)deg);
    gnn_hist<<<(N_EDGES + 255) / 256, 256, 0, stream>>>(ei, ea, ntype, deg);
    gnn_scanA<<<nScanBlk, 256, 0, stream>>>(deg, tmp, bsum);
    gnn_scanB<<<1, 512, 0, stream>>>(bsum, boff, nScanBlk);
    gnn_scanC<<<nScanBlk, 256, 0, stream>>>(tmp, deg, boff, off);
    gnn_scatter<<<(N_EDGES + 255) / 256, 256, 0, stream>>>(ei, ea, ntype, off, rec);

    // 1024 grid-stride blocks, 4/CU — layer 1 over sorted records
    gnn_edge_sorted<<<1024, 256, 0, stream>>>(xb, rec, off, W1, b1, hsumU);

    gnn_node_out<<<(N_NODES + 127) / 128, 256, 0, stream>>>(
        (const _Float16*)hsumU, deg, W2, b2, out);
}